// Round 1
// baseline (110.657 us; speedup 1.0000x reference)
//
#include <hip/hip_runtime.h>

#define B 4
#define TE 512
#define TD 256
#define D 256

#define C2    2.8853900817779268f   // 2/ln(2): exp(2x) = exp2(C2*x)
#define LOG2E 1.4426950408889634f

// 4-way division combine: q += sum_i v_i / p_i with ONE rcp.
// p products bounded by (e^13)^4 ~ 3e22 << FLT_MAX for these inputs.
__device__ __forceinline__ void qcomb4(float& q, const float4& v,
                                       float p0, float p1, float p2, float p3)
{
    const float n01 = fmaf(v.y, p0, v.x * p1);
    const float d01 = p0 * p1;
    const float n23 = fmaf(v.w, p2, v.z * p3);
    const float d23 = p2 * p3;
    const float num = fmaf(n23, d01, n01 * d23);
    const float den = d01 * d23;
    q = fmaf(num, __builtin_amdgcn_rcpf(den), q);
}

__device__ __forceinline__ void score4(float& q, const float4& v4,
                                       const float4& w, const float4& a)
{
    qcomb4(q, v4, fmaf(w.x, a.x, 1.0f), fmaf(w.y, a.y, 1.0f),
                  fmaf(w.z, a.z, 1.0f), fmaf(w.w, a.w, 1.0f));
}

// ---------------------------------------------------------------------------
// K1: enc projection + exp2 only (dec/eu moved into attn prologue).
// Grid 256 x 256 = exactly 1 block/CU, no tail.
// XCD-affine: blk%8 -> XCD; b = xcd>>1, so ewt[b] is produced (and later
// consumed) on XCD pair {2b, 2b+1} -> per-XCD hot set fits 4 MB L2.
// Output layout ewt4[b][dd][e] = float4 of d = 4dd..4dd+3 for encoder pos e:
// attn's score loads become lane-coalesced dwordx4 (8x fewer VMEM instrs).
// ---------------------------------------------------------------------------
__global__ __launch_bounds__(256) void proj_kernel(
    const float* __restrict__ enc, const float* __restrict__ Wa,
    float* __restrict__ ewt)
{
    __shared__ float a_lds[8 * 256];
    const int tid = threadIdx.x;
    const int blk = blockIdx.x;
    const int xcd = blk & 7;
    const int b   = xcd >> 1;
    const int j   = ((xcd & 1) << 5) | (blk >> 3);   // 0..63 e-slab within b
    const int e0  = j * 8;

    {
        const float4* src = (const float4*)(enc + ((size_t)(b * 512 + e0)) * 256);
        ((float4*)a_lds)[tid]       = src[tid];
        ((float4*)a_lds)[tid + 256] = src[tid + 256];
    }
    __syncthreads();

    float acc[8] = {0.f,0.f,0.f,0.f,0.f,0.f,0.f,0.f};

    #pragma unroll 4
    for (int k = 0; k < 256; k += 4) {
        const float w0 = Wa[(k + 0) * 256 + tid];
        const float w1 = Wa[(k + 1) * 256 + tid];
        const float w2 = Wa[(k + 2) * 256 + tid];
        const float w3 = Wa[(k + 3) * 256 + tid];
        #pragma unroll
        for (int r = 0; r < 8; r++) {
            const float4 a4 = *(const float4*)&a_lds[r * 256 + k];
            acc[r] = fmaf(a4.x, w0, acc[r]);
            acc[r] = fmaf(a4.y, w1, acc[r]);
            acc[r] = fmaf(a4.z, w2, acc[r]);
            acc[r] = fmaf(a4.w, w3, acc[r]);
        }
    }

    // scalar component stores into the float4 grid; threads d=0..3 + the 8
    // consecutive e's make each (dd, e-slab) region 128 B contiguous.
    float* o = ewt + (((size_t)(b * 64 + (tid >> 2)) * 512 + e0) << 2) + (tid & 3);
    #pragma unroll
    for (int r = 0; r < 8; r++)
        o[r * 4] = __builtin_amdgcn_exp2f(acc[r] * C2);
}

// ---------------------------------------------------------------------------
// K2: eu-prologue + fused score + softmax + context. One block per (b, t-quad),
// 256 blocks x 1024 threads, b-affine XCD mapping (same as K1).
// eu prologue: k-split dec@Ua (each Ua element read once per block, float4).
// Score: e = tid&511 serves ALL 4 t's over a d-half (tp = tid>>9); partials
//   combined via LDS. ewt loads: 32 dwordx4/thread (was 256 dwords).
// Softmax / context: unchanged from the 106 µs build.
// ---------------------------------------------------------------------------
__global__ __launch_bounds__(1024) void attn_kernel(
    const float* __restrict__ enc, const float* __restrict__ dec,
    const float* __restrict__ Ua,  const float* __restrict__ Va,
    const float* __restrict__ ewt,
    float* __restrict__ ctx, float* __restrict__ aw)
{
    __shared__ float eul[4 * 256];      // exp2(C2 * U_dec) for the 4 t's
    __shared__ float val[256];          // Va
    __shared__ float decl[4 * 256];     // staged dec rows
    __shared__ float sc[4][TE];         // scores -> weights (8 KB)
    __shared__ float wred[2][4][4];     // softmax cross-wave combine
    __shared__ float part[4][4][256];   // scratch: eu partials / score halves / ctx partials

    const int tid = threadIdx.x;
    const int blk = blockIdx.x;
    const int xcd = blk & 7;
    const int b   = xcd >> 1;                         // 2 XCDs per batch
    const int tq  = ((xcd & 1) << 5) | (blk >> 3);    // 0..63 t-quad
    const int t0  = tq * 4;
    const int bt0 = b * 256 + t0;

    float* const scratch = &part[0][0][0];            // 4096 floats

    if (tid < 256) val[tid] = Va[tid];
    decl[tid] = dec[(size_t)bt0 * 256 + tid];
    __syncthreads();

    // ---- eu prologue: eul[t][d] = exp2(C2 * (dec@Ua)[t][d]) -------------
    {
        const int dg = tid & 63;           // float4 column group (d = 4dg..4dg+3)
        const int t  = (tid >> 6) & 3;
        const int kq = tid >> 8;           // k-quarter: k in [64*kq, 64*kq+64)
        const float4* Ua4 = (const float4*)Ua;
        const float*  dr  = &decl[t * 256];
        float4 a4 = make_float4(0.f, 0.f, 0.f, 0.f);
        #pragma unroll 4
        for (int i = 0; i < 64; ++i) {
            const int k = kq * 64 + i;
            const float  dv = dr[k];                   // LDS broadcast
            const float4 u4 = Ua4[k * 64 + dg];        // coalesced
            a4.x = fmaf(dv, u4.x, a4.x);
            a4.y = fmaf(dv, u4.y, a4.y);
            a4.z = fmaf(dv, u4.z, a4.z);
            a4.w = fmaf(dv, u4.w, a4.w);
        }
        ((float4*)scratch)[(kq * 4 + t) * 64 + dg] = a4;   // partial[kq][t][d]
    }
    __syncthreads();
    {
        // tid = t*256+d; partial[kq] strides by 1024 floats
        const float s = scratch[tid] + scratch[1024 + tid] +
                        scratch[2048 + tid] + scratch[3072 + tid];
        eul[tid] = __builtin_amdgcn_exp2f(s * C2);
    }
    __syncthreads();

    // ---- scores: score'[t][e] = -2 * sum_d v_d / (1 + Ew*Eu) ------------
    {
        const int e  = tid & 511;
        const int tp = tid >> 9;           // d-half: d in [128*tp, 128*tp+128)
        const float4* __restrict__ ewb =
            (const float4*)ewt + (size_t)(b * 64 + tp * 32) * 512 + e;
        float q0 = 0.f, q1 = 0.f, q2 = 0.f, q3 = 0.f;

        #pragma unroll 2
        for (int it = 0; it < 16; ++it) {
            const float4 w0 = ewb[(it * 2 + 0) * 512];   // d-quad 2it
            const float4 w1 = ewb[(it * 2 + 1) * 512];   // d-quad 2it+1
            const int d0 = (tp * 32 + it * 2) * 4;
            {
                const float4 v4 = *(const float4*)&val[d0];
                score4(q0, v4, w0, *(const float4*)&eul[      d0]);
                score4(q1, v4, w0, *(const float4*)&eul[256 + d0]);
                score4(q2, v4, w0, *(const float4*)&eul[512 + d0]);
                score4(q3, v4, w0, *(const float4*)&eul[768 + d0]);
            }
            {
                const int d1 = d0 + 4;
                const float4 v4 = *(const float4*)&val[d1];
                score4(q0, v4, w1, *(const float4*)&eul[      d1]);
                score4(q1, v4, w1, *(const float4*)&eul[256 + d1]);
                score4(q2, v4, w1, *(const float4*)&eul[512 + d1]);
                score4(q3, v4, w1, *(const float4*)&eul[768 + d1]);
            }
        }

        if (tp) {
            scratch[       e] = q0;
            scratch[512  + e] = q1;
            scratch[1024 + e] = q2;
            scratch[1536 + e] = q3;
        }
        __syncthreads();
        if (!tp) {
            sc[0][e] = -2.0f * (q0 + scratch[       e]);
            sc[1][e] = -2.0f * (q1 + scratch[512  + e]);
            sc[2][e] = -2.0f * (q2 + scratch[1024 + e]);
            sc[3][e] = -2.0f * (q3 + scratch[1536 + e]);
        }
    }
    __syncthreads();

    // ---- softmax: wave wv -> (t = wv>>2, seg = wv&3) ---------------------
    {
        const int wv   = tid >> 6;
        const int lane = tid & 63;
        const int t    = wv >> 2;
        const int seg  = wv & 3;
        float* __restrict__ srow = &sc[t][seg * 128];

        const float x0 = srow[lane];
        const float x1 = srow[lane + 64];

        float m = fmaxf(x0, x1);
        #pragma unroll
        for (int s = 32; s > 0; s >>= 1) m = fmaxf(m, __shfl_xor(m, s, 64));
        if (lane == 0) wred[0][t][seg] = m;
        __syncthreads();
        const float4 mm = *(const float4*)&wred[0][t][0];
        const float M = fmaxf(fmaxf(mm.x, mm.y), fmaxf(mm.z, mm.w));

        const float g0 = __builtin_amdgcn_exp2f((x0 - M) * LOG2E);
        const float g1 = __builtin_amdgcn_exp2f((x1 - M) * LOG2E);

        float ssum = g0 + g1;
        #pragma unroll
        for (int s = 32; s > 0; s >>= 1) ssum += __shfl_xor(ssum, s, 64);
        if (lane == 0) wred[1][t][seg] = ssum;
        __syncthreads();
        const float4 sm = *(const float4*)&wred[1][t][0];
        const float inv = __builtin_amdgcn_rcpf((sm.x + sm.y) + (sm.z + sm.w));

        const float p0 = g0 * inv, p1 = g1 * inv;
        srow[lane]      = p0;
        srow[lane + 64] = p1;
        float* __restrict__ ao = aw + ((size_t)(bt0 + t)) * 512 + seg * 128;
        ao[lane]      = p0;
        ao[lane + 64] = p1;
    }
    __syncthreads();

    // ---- context: eg = tid>>8 (128 e's each), dl = tid&255 ---------------
    {
        const int eg = tid >> 8;
        const int dl = tid & 255;
        const float* __restrict__ eb =
            enc + ((size_t)b * 512 + eg * 128) * 256 + dl;
        const int e0 = eg * 128;

        float c0 = 0.f, c1 = 0.f, c2 = 0.f, c3 = 0.f;
        #pragma unroll 4
        for (int jj = 0; jj < 128; jj += 4) {
            const float4 w0 = *(const float4*)&sc[0][e0 + jj];
            const float4 w1 = *(const float4*)&sc[1][e0 + jj];
            const float4 w2 = *(const float4*)&sc[2][e0 + jj];
            const float4 w3 = *(const float4*)&sc[3][e0 + jj];
            const float r0 = eb[(jj + 0) * 256];
            const float r1 = eb[(jj + 1) * 256];
            const float r2 = eb[(jj + 2) * 256];
            const float r3 = eb[(jj + 3) * 256];
            c0 = fmaf(w0.x, r0, c0); c0 = fmaf(w0.y, r1, c0); c0 = fmaf(w0.z, r2, c0); c0 = fmaf(w0.w, r3, c0);
            c1 = fmaf(w1.x, r0, c1); c1 = fmaf(w1.y, r1, c1); c1 = fmaf(w1.z, r2, c1); c1 = fmaf(w1.w, r3, c1);
            c2 = fmaf(w2.x, r0, c2); c2 = fmaf(w2.y, r1, c2); c2 = fmaf(w2.z, r2, c2); c2 = fmaf(w2.w, r3, c2);
            c3 = fmaf(w3.x, r0, c3); c3 = fmaf(w3.y, r1, c3); c3 = fmaf(w3.z, r2, c3); c3 = fmaf(w3.w, r3, c3);
        }
        part[eg][0][dl] = c0;
        part[eg][1][dl] = c1;
        part[eg][2][dl] = c2;
        part[eg][3][dl] = c3;
    }
    __syncthreads();

    {
        const int t  = tid >> 8;       // 0..3
        const int dl = tid & 255;
        ctx[((size_t)(bt0 + t)) * 256 + dl] =
            (part[0][t][dl] + part[1][t][dl]) +
            (part[2][t][dl] + part[3][t][dl]);
    }
}

extern "C" void kernel_launch(void* const* d_in, const int* in_sizes, int n_in,
                              void* d_out, int out_size, void* d_ws, size_t ws_size,
                              hipStream_t stream) {
    const float* enc = (const float*)d_in[0];   // [4,512,256]
    const float* dec = (const float*)d_in[1];   // [4,256,256]
    const float* Wa  = (const float*)d_in[2];   // [256,256]
    const float* Ua  = (const float*)d_in[3];   // [256,256]
    const float* Va  = (const float*)d_in[4];   // [256,1]

    float* out = (float*)d_out;
    float* ctx = out;                           // [4,256,256]
    float* aw  = out + B * TD * D;              // [4,256,512]

    float* ewt = (float*)d_ws;                  // [4][64 dd][512 e] float4, 2 MB

    proj_kernel<<<dim3(256), dim3(256),  0, stream>>>(enc, Wa, ewt);
    attn_kernel<<<dim3(256), dim3(1024), 0, stream>>>(enc, dec, Ua, Va, ewt, ctx, aw);
}